// Round 4
// baseline (1129.021 us; speedup 1.0000x reference)
//
#include <hip/hip_runtime.h>

// R4: conv K-loop restructured for tap-reuse. Per (di,kc): stage a 130-token A
// window ONCE (ldsdma, swizzle folded into global addr, guarded tail phase) and
// B for tap-group {dj=0,1}; barrier; 64 MFMAs; barrier; restage B for {dj=2};
// barrier; 32 MFMAs; barrier. Periods 18->12, LDS 32->49.4KB but occupancy
// 2->3 blocks/CU (launch_bounds(256,3)). A-frag row = dj + ra (free 2-way LDS
// conflicts). All other kernels unchanged from R3.
// Per-batch workspace (reused for b=0,1): total 154,012,672 B
//   padx  f16 [258][258][128]  @ 0           (17,040,384)
//   wcat  f16 [9][1024][128]   @ 17,040,384  ( 2,359,296)
//   ST    f32 [8][64][64]      @ 19,399,680  (   131,072)  memset 0 per batch
//   norm  f32 [8][64]          @ 19,530,752  (     2,048)  memset 0 per batch
//   OS    f32 [8][64][64]      @ 19,532,800  (   131,072)
//   PT    f16 [128][512]       @ 19,663,872  (   131,072)
//   xmid  f16 [65536][512]     @ 19,794,944  (67,108,864)  x_mid, overlaid by W
//   fxT   f16 [512][65536]     @ 86,903,808  (67,108,864)  fx transposed

typedef _Float16 f16;
typedef _Float16 f16x8 __attribute__((ext_vector_type(8)));
typedef float    f32x4 __attribute__((ext_vector_type(4)));

static const size_t OFF_PADX = 0;
static const size_t OFF_WCAT = 17040384;
static const size_t OFF_ST   = 19399680;
static const size_t OFF_NORM = 19530752;
static const size_t OFF_OS   = 19532800;
static const size_t OFF_PT   = 19663872;
static const size_t OFF_XMID = 19794944;
static const size_t OFF_FXT  = 86903808;

__device__ __forceinline__ void ldsdma16(f16* lds, const f16* g) {
  __builtin_amdgcn_global_load_lds((__attribute__((address_space(1))) void*)g,
                                   (__attribute__((address_space(3))) void*)lds,
                                   16, 0, 0);
}

// ---------------------------------------------------------------- pad + cast x
__global__ __launch_bounds__(256) void pad_kernel(const float* __restrict__ xb,
                                                  f16* __restrict__ padx) {
  int idx = blockIdx.x * 256 + threadIdx.x;           // over [258][258][16]
  if (idx >= 258 * 258 * 16) return;
  int c8 = (idx & 15) * 8;
  int r  = idx >> 4;                                  // ip*258 + jp
  int jp = r % 258;
  int ip = r / 258;
  f16x8 v;
  if (ip == 0 || ip == 257 || jp == 0 || jp == 257) {
#pragma unroll
    for (int j = 0; j < 8; ++j) v[j] = (f16)0.0f;
  } else {
    const float* src = xb + ((size_t)(ip - 1) * 256 + (jp - 1)) * 128 + c8;
#pragma unroll
    for (int j = 0; j < 8; ++j) v[j] = (f16)src[j];
  }
  *(f16x8*)(padx + (size_t)r * 128 + c8) = v;
}

// ------------------------------------------- weights: Wcat_T[tap][co(1024)][ci]
__global__ __launch_bounds__(256) void prepw_kernel(const float* __restrict__ Wfx,
                                                    const float* __restrict__ Wx,
                                                    f16* __restrict__ wcat) {
  int idx = blockIdx.x * 256 + threadIdx.x;           // (tap*1024+co)*128+ci
  if (idx >= 9 * 1024 * 128) return;
  int ci = idx & 127;
  int t  = idx >> 7;
  int co = t & 1023;
  int tap = t >> 10;
  float v = (co < 512) ? Wfx[(size_t)(tap * 128 + ci) * 512 + co]
                       : Wx[(size_t)(tap * 128 + ci) * 512 + (co - 512)];
  wcat[idx] = (f16)v;
}

// --------------------------------------------------- fused conv: implicit GEMM
// tile M=128 tokens x N=128 out-ch; A window (130 tokens) staged once per
// (di,kc), B staged in tap-groups {0,1} then {2}.
__global__ __launch_bounds__(256, 3) void conv_kernel(const f16* __restrict__ padx,
                                                      const f16* __restrict__ wcat,
                                                      const float* __restrict__ bfx,
                                                      const float* __restrict__ bx,
                                                      f16* __restrict__ xmid,
                                                      f16* __restrict__ fxT) {
  __shared__ f16 As[130 * 64];       // 16,640 B: slot s = t*8+c holds row t, chunk c^(t&7)
  __shared__ f16 Bs[2 * 128 * 64];   // 32,768 B: two taps, same swizzled layout
  int tid = threadIdx.x;
  int nt = blockIdx.x & 7;
  int mt = blockIdx.x >> 3;          // 0..511
  int i  = mt >> 1;
  int j0 = (mt & 1) * 128;
  int n0 = nt * 128;
  int lane = tid & 63, wave = tid >> 6;
  int ln15 = lane & 15, quad = lane >> 4;
  int wm = wave & 1, wn = wave >> 1;

  f32x4 acc[4][4] = {};

  for (int di = 0; di < 3; ++di) {
    const f16* aRow = padx + ((size_t)(i + di) * 258 + j0) * 128;
    for (int kc = 0; kc < 128; kc += 64) {
      // ---- stage A: 130 rows x 8 chunks = 1040 slots (guarded 5th phase)
#pragma unroll
      for (int ph = 0; ph < 5; ++ph) {
        int s = ph * 256 + tid;
        if (s < 1040) {
          int rr = s >> 3;
          int qq = ((s & 7) ^ (rr & 7)) * 8;
          ldsdma16(&As[(ph * 256 + wave * 64) * 8], aRow + (size_t)rr * 128 + kc + qq);
        }
      }
      // ---- stage B taps di*3+{0,1}: 2048 slots
#pragma unroll
      for (int ph = 0; ph < 8; ++ph) {
        int s2 = ph * 256 + tid;
        int dj = s2 >> 10;
        int sB = s2 & 1023;
        int rr = sB >> 3;
        int qq = ((sB & 7) ^ (rr & 7)) * 8;
        ldsdma16(&Bs[(ph * 256 + wave * 64) * 8],
                 wcat + ((size_t)((di * 3 + dj) * 1024 + n0 + rr)) * 128 + kc + qq);
      }
      __syncthreads();
      // ---- MFMA group 0: dj = 0,1
#pragma unroll
      for (int dj = 0; dj < 2; ++dj) {
#pragma unroll
        for (int ks = 0; ks < 2; ++ks) {
          int q = ks * 4 + quad;
          f16x8 af[4], bfr[4];
#pragma unroll
          for (int xx = 0; xx < 4; ++xx) {
            int t  = dj + wm * 64 + xx * 16 + ln15;
            int rb = wn * 64 + xx * 16 + ln15;
            af[xx]  = *(const f16x8*)(&As[t * 64 + ((q ^ (t & 7)) * 8)]);
            bfr[xx] = *(const f16x8*)(&Bs[dj * 8192 + rb * 64 + ((q ^ (rb & 7)) * 8)]);
          }
#pragma unroll
          for (int mf = 0; mf < 4; ++mf)
#pragma unroll
            for (int nf = 0; nf < 4; ++nf)
              acc[mf][nf] = __builtin_amdgcn_mfma_f32_16x16x32_f16(af[mf], bfr[nf],
                                                                   acc[mf][nf], 0, 0, 0);
        }
      }
      __syncthreads();
      // ---- restage B tap di*3+2 into Bs[0]
#pragma unroll
      for (int ph = 0; ph < 4; ++ph) {
        int sB = ph * 256 + tid;
        int rr = sB >> 3;
        int qq = ((sB & 7) ^ (rr & 7)) * 8;
        ldsdma16(&Bs[(ph * 256 + wave * 64) * 8],
                 wcat + ((size_t)((di * 3 + 2) * 1024 + n0 + rr)) * 128 + kc + qq);
      }
      __syncthreads();
      // ---- MFMA group 1: dj = 2
#pragma unroll
      for (int ks = 0; ks < 2; ++ks) {
        int q = ks * 4 + quad;
        f16x8 af[4], bfr[4];
#pragma unroll
        for (int xx = 0; xx < 4; ++xx) {
          int t  = 2 + wm * 64 + xx * 16 + ln15;
          int rb = wn * 64 + xx * 16 + ln15;
          af[xx]  = *(const f16x8*)(&As[t * 64 + ((q ^ (t & 7)) * 8)]);
          bfr[xx] = *(const f16x8*)(&Bs[rb * 64 + ((q ^ (rb & 7)) * 8)]);
        }
#pragma unroll
        for (int mf = 0; mf < 4; ++mf)
#pragma unroll
          for (int nf = 0; nf < 4; ++nf)
            acc[mf][nf] = __builtin_amdgcn_mfma_f32_16x16x32_f16(af[mf], bfr[nf],
                                                                 acc[mf][nf], 0, 0, 0);
      }
      __syncthreads();
    }
  }

  size_t token0 = (size_t)i * 256 + j0;
#pragma unroll
  for (int nf = 0; nf < 4; ++nf) {
    int col = n0 + wn * 64 + nf * 16 + ln15;
    float bias = (col < 512) ? bfx[col] : bx[col - 512];
#pragma unroll
    for (int mf = 0; mf < 4; ++mf) {
      int rbase = wm * 64 + mf * 16 + quad * 4;
#pragma unroll
      for (int v = 0; v < 4; ++v) {
        int token = token0 + rbase + v;
        f16 val = (f16)(acc[mf][nf][v] + bias);
        if (col < 512) fxT[(size_t)col * 65536 + token] = val;
        else           xmid[(size_t)token * 512 + (col - 512)] = val;
      }
    }
  }
}

// ---------------- slice: MFMA logits -> shfl softmax -> W overlay + MFMA ST acc
#define WS_S 72
#define WT_S 264
__global__ __launch_bounds__(256, 2) void slice_kernel(f16* __restrict__ xmid,
                                                       const f16* __restrict__ fxT,
                                                       const float* __restrict__ Wslice,
                                                       const float* __restrict__ bslice,
                                                       const float* __restrict__ temperature,
                                                       float* __restrict__ ST,
                                                       float* __restrict__ snorm) {
  __shared__ f16 Ws[64 * WS_S];      // [g][d] f16, padded
  __shared__ f16 Wt[64 * WT_S];      // [g][t_local 256] padded, wave-private t-stripes
  __shared__ float red[64 * 65];     // cross-wave ST reduction
  __shared__ float redn[64];
  int tid = threadIdx.x;
  int h = blockIdx.x >> 6;           // 8
  int chunk = blockIdx.x & 63;       // 64 chunks of 1024 tokens
  int tok0 = chunk * 1024;
  int lane = tid & 63, wave = tid >> 6;
  int ln15 = lane & 15, quad = lane >> 4;

  for (int s = tid; s < 4096; s += 256)
    Ws[(s >> 6) * WS_S + (s & 63)] = (f16)Wslice[s];
  if (tid < 64) redn[tid] = 0.f;
  float tc = temperature[h];
  tc = fminf(fmaxf(tc, 0.1f), 5.0f);
  float invt = 1.0f / tc;
  float bsv[4];
#pragma unroll
  for (int nf = 0; nf < 4; ++nf) bsv[nf] = bslice[nf * 16 + ln15];
  __syncthreads();

  f32x4 acc2[4][4] = {};             // ST partial: [mf->g][nf->d]
  float naccv[4] = {};               // norm partial per nf (g = nf*16+ln15)

  for (int it = 0; it < 4; ++it) {
    int tsub = it * 256 + wave * 64;            // this wave's 64 tokens (local)
    // ---- phase A: logits via MFMA (A direct from global, B from LDS Ws)
    f32x4 accA[4][4] = {};
#pragma unroll
    for (int kq = 0; kq < 2; ++kq) {
      f16x8 bf[4];
#pragma unroll
      for (int nf = 0; nf < 4; ++nf)
        bf[nf] = *(const f16x8*)(&Ws[(nf * 16 + ln15) * WS_S + kq * 32 + quad * 8]);
#pragma unroll
      for (int mf = 0; mf < 4; ++mf) {
        f16x8 af = *(const f16x8*)(xmid + (size_t)(tok0 + tsub + mf * 16 + ln15) * 512 +
                                   h * 64 + kq * 32 + quad * 8);
#pragma unroll
        for (int nf = 0; nf < 4; ++nf)
          accA[mf][nf] = __builtin_amdgcn_mfma_f32_16x16x32_f16(af, bf[nf], accA[mf][nf],
                                                                0, 0, 0);
      }
    }
    // ---- softmax over g (4 in-lane nf x 16 lanes), write W overlay + Wt
#pragma unroll
    for (int mf = 0; mf < 4; ++mf) {
#pragma unroll
      for (int v = 0; v < 4; ++v) {
        float l[4];
#pragma unroll
        for (int nf = 0; nf < 4; ++nf) l[nf] = (accA[mf][nf][v] + bsv[nf]) * invt;
        float lm = fmaxf(fmaxf(l[0], l[1]), fmaxf(l[2], l[3]));
#pragma unroll
        for (int off = 1; off < 16; off <<= 1) lm = fmaxf(lm, __shfl_xor(lm, off, 64));
        float e[4], ssum = 0.f;
#pragma unroll
        for (int nf = 0; nf < 4; ++nf) { e[nf] = __expf(l[nf] - lm); ssum += e[nf]; }
#pragma unroll
        for (int off = 1; off < 16; off <<= 1) ssum += __shfl_xor(ssum, off, 64);
        float winv = 1.0f / ssum;
        int t_loc = tsub + mf * 16 + quad * 4 + v;       // local to 1024-chunk
        int t_str = wave * 64 + mf * 16 + quad * 4 + v;  // local to 256-stripe set
        f16* wrow = xmid + (size_t)(tok0 + t_loc) * 512 + h * 64;
#pragma unroll
        for (int nf = 0; nf < 4; ++nf) {
          float w = e[nf] * winv;
          naccv[nf] += w;
          f16 wh = (f16)w;
          wrow[nf * 16 + ln15] = wh;
          Wt[(nf * 16 + ln15) * WT_S + t_str] = wh;
        }
      }
    }
    // ---- phase B: acc2[g][d] += Wt^T-frag x fxT-frag (wave-private k-range)
#pragma unroll
    for (int kq = 0; kq < 2; ++kq) {
      int kof = wave * 64 + kq * 32 + quad * 8;          // within 256-stripe set
      f16x8 bfB[4];
#pragma unroll
      for (int nf = 0; nf < 4; ++nf)
        bfB[nf] = *(const f16x8*)(fxT + (size_t)(h * 64 + nf * 16 + ln15) * 65536 +
                                  tok0 + it * 256 + kof);
#pragma unroll
      for (int mf = 0; mf < 4; ++mf) {
        f16x8 afB = *(const f16x8*)(&Wt[(mf * 16 + ln15) * WT_S + kof]);
#pragma unroll
        for (int nf = 0; nf < 4; ++nf)
          acc2[mf][nf] = __builtin_amdgcn_mfma_f32_16x16x32_f16(afB, bfB[nf],
                                                                acc2[mf][nf], 0, 0, 0);
      }
    }
  }

  // ---- norm partials into LDS (16 contributors per g)
#pragma unroll
  for (int nf = 0; nf < 4; ++nf) atomicAdd(&redn[nf * 16 + ln15], naccv[nf]);

  // ---- cross-wave ST reduce + global atomics
  for (int s = 0; s < 4; ++s) {
    if (wave == s) {
#pragma unroll
      for (int mf = 0; mf < 4; ++mf)
#pragma unroll
        for (int nf = 0; nf < 4; ++nf)
#pragma unroll
          for (int v = 0; v < 4; ++v) {
            int g = mf * 16 + quad * 4 + v;
            int d = nf * 16 + ln15;
            if (s == 0) red[g * 65 + d] = acc2[mf][nf][v];
            else        red[g * 65 + d] += acc2[mf][nf][v];
          }
    }
    __syncthreads();
  }
  float* stp = ST + (size_t)h * 4096;
  for (int s2 = tid; s2 < 4096; s2 += 256)
    atomicAdd(&stp[s2], red[(s2 >> 6) * 65 + (s2 & 63)]);
  if (tid < 64) atomicAdd(&snorm[h * 64 + tid], redn[tid]);
}

// ------------------------------------------ tiny attention over 64 slice tokens
__global__ __launch_bounds__(256) void attn_kernel(const float* __restrict__ ST,
                                                   const float* __restrict__ snorm,
                                                   const float* __restrict__ Wq,
                                                   const float* __restrict__ Wk,
                                                   const float* __restrict__ Wv,
                                                   float* __restrict__ OS) {
  int h = blockIdx.x;                // 8
  __shared__ float tok[64 * 65];     // aliased as scores later
  __shared__ float qs[64 * 65];
  __shared__ float ksm[64 * 65];
  __shared__ f16 vsm[64 * 65];
  int tid = threadIdx.x;
  const float* stp = ST + (size_t)h * 4096;
  const float* snp = snorm + (size_t)h * 64;
  for (int s = tid; s < 4096; s += 256) {
    int g = s >> 6, d = s & 63;
    tok[g * 65 + d] = stp[s] / (snp[g] + 1e-5f);
  }
  __syncthreads();
  int g = tid >> 2, p16 = (tid & 3) * 16;
  for (int e0 = 0; e0 < 16; ++e0) {
    int e = p16 + e0;
    const float* wq = Wq + e * 64;
    const float* wk = Wk + e * 64;
    const float* wv = Wv + e * 64;
    float aq = 0, ak = 0, av = 0;
#pragma unroll 8
    for (int d = 0; d < 64; ++d) {
      float tv = tok[g * 65 + d];
      aq += tv * wq[d];
      ak += tv * wk[d];
      av += tv * wv[d];
    }
    qs[g * 65 + e] = aq;
    ksm[g * 65 + e] = ak;
    vsm[g * 65 + e] = (f16)av;
  }
  __syncthreads();
  float* sc = tok;  // alias, tok dead
  for (int f0 = 0; f0 < 16; ++f0) {
    int f = p16 + f0;
    float s = 0;
#pragma unroll 8
    for (int e = 0; e < 64; ++e) s += qs[g * 65 + e] * ksm[f * 65 + e];
    sc[g * 65 + f] = s * 0.125f;
  }
  __syncthreads();
  if (tid < 64) {
    float m = -1e30f;
    for (int f = 0; f < 64; ++f) m = fmaxf(m, sc[tid * 65 + f]);
    float ssum = 0;
    for (int f = 0; f < 64; ++f) {
      float e = __expf(sc[tid * 65 + f] - m);
      sc[tid * 65 + f] = e;
      ssum += e;
    }
    float inv = 1.0f / ssum;
    for (int f = 0; f < 64; ++f) sc[tid * 65 + f] *= inv;
  }
  __syncthreads();
  for (int e0 = 0; e0 < 16; ++e0) {
    int e = p16 + e0;
    float o = 0;
#pragma unroll 8
    for (int f = 0; f < 64; ++f) o += sc[g * 65 + f] * (float)vsm[f * 65 + e];
    OS[(size_t)h * 4096 + g * 64 + e] = o;
  }
}

// -------------------------- fold out_slice into Wout: PT[o][h*64+g] (f16)
__global__ __launch_bounds__(256) void pt_kernel(const float* __restrict__ OS,
                                                 const float* __restrict__ Wout,
                                                 f16* __restrict__ PT) {
  int h = blockIdx.x;                // 8
  __shared__ float os[64 * 65];
  int tid = threadIdx.x;
  for (int s = tid; s < 4096; s += 256) os[(s >> 6) * 65 + (s & 63)] = OS[(size_t)h * 4096 + s];
  __syncthreads();
  int o = tid >> 1, gh = (tid & 1) * 32;
  const float* wr = Wout + (size_t)o * 512 + h * 64;
  float wreg[64];
#pragma unroll
  for (int d = 0; d < 64; ++d) wreg[d] = wr[d];
  for (int gg = 0; gg < 32; ++gg) {
    int g = gh + gg;
    float s = 0;
#pragma unroll
    for (int d = 0; d < 64; ++d) s += os[g * 65 + d] * wreg[d];
    PT[(size_t)o * 512 + h * 64 + g] = (f16)s;
  }
}

// -------------------- final: out[n,o] = sum_k W[n,k] * PT[o,k] + bout[o]
__global__ __launch_bounds__(256, 2) void final_kernel(const f16* __restrict__ xmid,
                                                       const f16* __restrict__ PT,
                                                       const float* __restrict__ bout,
                                                       float* __restrict__ outb) {
  __shared__ f16 As[128 * 64];
  __shared__ f16 Bs[128 * 64];
  int tid = threadIdx.x;
  int tok0 = blockIdx.x << 7;        // 512 blocks
  int lane = tid & 63, wave = tid >> 6;
  int ln15 = lane & 15, quad = lane >> 4;
  int wm = wave & 1, wn = wave >> 1;
  int rr[4], qq8[4];
#pragma unroll
  for (int ph = 0; ph < 4; ++ph) {
    int s = ph * 256 + tid;
    rr[ph] = s >> 3;
    qq8[ph] = ((s & 7) ^ (rr[ph] & 7)) * 8;
  }
  int wbase = wave * 512;
  f32x4 acc[4][4] = {};
  const f16* aB = xmid + (size_t)tok0 * 512;
  const f16* bB = PT;
  for (int kc = 0; kc < 512; kc += 64) {
#pragma unroll
    for (int ph = 0; ph < 4; ++ph) {
      ldsdma16(&As[ph * 2048 + wbase], aB + (size_t)rr[ph] * 512 + kc + qq8[ph]);
      ldsdma16(&Bs[ph * 2048 + wbase], bB + (size_t)rr[ph] * 512 + kc + qq8[ph]);
    }
    __syncthreads();
#pragma unroll
    for (int ks = 0; ks < 2; ++ks) {
      f16x8 af[4], bfr[4];
      int q = ks * 4 + quad;
#pragma unroll
      for (int xx = 0; xx < 4; ++xx) {
        int ra = wm * 64 + xx * 16 + ln15;
        int rb = wn * 64 + xx * 16 + ln15;
        af[xx]  = *(const f16x8*)(&As[ra * 64 + (q ^ (ra & 7)) * 8]);
        bfr[xx] = *(const f16x8*)(&Bs[rb * 64 + (q ^ (rb & 7)) * 8]);
      }
#pragma unroll
      for (int mf = 0; mf < 4; ++mf)
#pragma unroll
        for (int nf = 0; nf < 4; ++nf)
          acc[mf][nf] = __builtin_amdgcn_mfma_f32_16x16x32_f16(af[mf], bfr[nf],
                                                               acc[mf][nf], 0, 0, 0);
    }
    __syncthreads();
  }
#pragma unroll
  for (int nf = 0; nf < 4; ++nf) {
    int col = wn * 64 + nf * 16 + ln15;
    float bo = bout[col];
#pragma unroll
    for (int mf = 0; mf < 4; ++mf) {
      int rbase = wm * 64 + mf * 16 + quad * 4;
#pragma unroll
      for (int v = 0; v < 4; ++v)
        outb[(size_t)(tok0 + rbase + v) * 128 + col] = acc[mf][nf][v] + bo;
    }
  }
}

extern "C" void kernel_launch(void* const* d_in, const int* in_sizes, int n_in,
                              void* d_out, int out_size, void* d_ws, size_t ws_size,
                              hipStream_t stream) {
  const float* x    = (const float*)d_in[0];
  const float* Wfx  = (const float*)d_in[1];
  const float* bfx  = (const float*)d_in[2];
  const float* Wx   = (const float*)d_in[3];
  const float* bx   = (const float*)d_in[4];
  const float* Wsl  = (const float*)d_in[5];
  const float* bsl  = (const float*)d_in[6];
  const float* temp = (const float*)d_in[7];
  const float* Wq   = (const float*)d_in[8];
  const float* Wk   = (const float*)d_in[9];
  const float* Wv   = (const float*)d_in[10];
  const float* Wout = (const float*)d_in[11];
  const float* bout = (const float*)d_in[12];
  float* out = (float*)d_out;
  char* ws = (char*)d_ws;

  f16*  padx = (f16*)(ws + OFF_PADX);
  f16*  wcat = (f16*)(ws + OFF_WCAT);
  float* ST  = (float*)(ws + OFF_ST);
  float* nrm = (float*)(ws + OFF_NORM);
  float* OS  = (float*)(ws + OFF_OS);
  f16*  PT   = (f16*)(ws + OFF_PT);
  f16*  xmid = (f16*)(ws + OFF_XMID);
  f16*  fxT  = (f16*)(ws + OFF_FXT);

  prepw_kernel<<<4608, 256, 0, stream>>>(Wfx, Wx, wcat);
  for (int b = 0; b < 2; ++b) {
    const float* xb = x + (size_t)b * 65536 * 128;
    float* outb = out + (size_t)b * 65536 * 128;
    hipMemsetAsync(ws + OFF_ST, 0, 131072 + 2048, stream);  // ST + norm
    pad_kernel<<<4161, 256, 0, stream>>>(xb, padx);
    conv_kernel<<<4096, 256, 0, stream>>>(padx, wcat, bfx, bx, xmid, fxT);
    slice_kernel<<<512, 256, 0, stream>>>(xmid, fxT, Wsl, bsl, temp, ST, nrm);
    attn_kernel<<<8, 256, 0, stream>>>(ST, nrm, Wq, Wk, Wv, OS);
    pt_kernel<<<8, 256, 0, stream>>>(OS, Wout, PT);
    final_kernel<<<512, 256, 0, stream>>>(xmid, PT, bout, outb);
  }
}

// Round 5
// 844.751 us; speedup vs baseline: 1.3365x; 1.3365x over previous
//
#include <hip/hip_runtime.h>

// R5: conv tap-reuse retained but with the two R4 regression causes removed:
//  (1) 2 blocks/CU (launch_bounds(256,2), LDS 64.6 KB) — R4's 3/CU thrashed the
//      4 MB per-XCD L2 (FETCH 77->323 MB);
//  (2) fxT epilogue routed through an LDS transpose tile so global stores are
//      f16x8 (256 B contiguous per 16 lanes) — kills the 8B-per-lane scatter
//      whose partial-line RMW inflated FETCH+WRITE.
//  K-loop: per (di,kc): stage A window (130 tokens) + all 3 dj taps of B; ONE
//  barrier pair; 96 MFMAs/wave. 6 periods total (R3: 18, R4: 12).
// Other kernels unchanged from R3. Per-batch workspace (total 154,012,672 B):
//   padx  f16 [258][258][128]  @ 0           (17,040,384)
//   wcat  f16 [9][1024][128]   @ 17,040,384  ( 2,359,296)
//   ST    f32 [8][64][64]      @ 19,399,680  (   131,072)  memset 0 per batch
//   norm  f32 [8][64]          @ 19,530,752  (     2,048)  memset 0 per batch
//   OS    f32 [8][64][64]      @ 19,532,800  (   131,072)
//   PT    f16 [128][512]       @ 19,663,872  (   131,072)
//   xmid  f16 [65536][512]     @ 19,794,944  (67,108,864)
//   fxT   f16 [512][65536]     @ 86,903,808  (67,108,864)

typedef _Float16 f16;
typedef _Float16 f16x8 __attribute__((ext_vector_type(8)));
typedef _Float16 f16x4 __attribute__((ext_vector_type(4)));
typedef float    f32x4 __attribute__((ext_vector_type(4)));

static const size_t OFF_PADX = 0;
static const size_t OFF_WCAT = 17040384;
static const size_t OFF_ST   = 19399680;
static const size_t OFF_NORM = 19530752;
static const size_t OFF_OS   = 19532800;
static const size_t OFF_PT   = 19663872;
static const size_t OFF_XMID = 19794944;
static const size_t OFF_FXT  = 86903808;

__device__ __forceinline__ void ldsdma16(f16* lds, const f16* g) {
  __builtin_amdgcn_global_load_lds((__attribute__((address_space(1))) void*)g,
                                   (__attribute__((address_space(3))) void*)lds,
                                   16, 0, 0);
}

// ---------------------------------------------------------------- pad + cast x
__global__ __launch_bounds__(256) void pad_kernel(const float* __restrict__ xb,
                                                  f16* __restrict__ padx) {
  int idx = blockIdx.x * 256 + threadIdx.x;           // over [258][258][16]
  if (idx >= 258 * 258 * 16) return;
  int c8 = (idx & 15) * 8;
  int r  = idx >> 4;                                  // ip*258 + jp
  int jp = r % 258;
  int ip = r / 258;
  f16x8 v;
  if (ip == 0 || ip == 257 || jp == 0 || jp == 257) {
#pragma unroll
    for (int j = 0; j < 8; ++j) v[j] = (f16)0.0f;
  } else {
    const float* src = xb + ((size_t)(ip - 1) * 256 + (jp - 1)) * 128 + c8;
#pragma unroll
    for (int j = 0; j < 8; ++j) v[j] = (f16)src[j];
  }
  *(f16x8*)(padx + (size_t)r * 128 + c8) = v;
}

// ------------------------------------------- weights: Wcat_T[tap][co(1024)][ci]
__global__ __launch_bounds__(256) void prepw_kernel(const float* __restrict__ Wfx,
                                                    const float* __restrict__ Wx,
                                                    f16* __restrict__ wcat) {
  int idx = blockIdx.x * 256 + threadIdx.x;           // (tap*1024+co)*128+ci
  if (idx >= 9 * 1024 * 128) return;
  int ci = idx & 127;
  int t  = idx >> 7;
  int co = t & 1023;
  int tap = t >> 10;
  float v = (co < 512) ? Wfx[(size_t)(tap * 128 + ci) * 512 + co]
                       : Wx[(size_t)(tap * 128 + ci) * 512 + (co - 512)];
  wcat[idx] = (f16)v;
}

// --------------------------------------------------- fused conv: implicit GEMM
__global__ __launch_bounds__(256, 2) void conv_kernel(const f16* __restrict__ padx,
                                                      const f16* __restrict__ wcat,
                                                      const float* __restrict__ bfx,
                                                      const float* __restrict__ bx,
                                                      f16* __restrict__ xmid,
                                                      f16* __restrict__ fxT) {
  __shared__ f16 As[130 * 64];       // 16,640 B; slot s=t*8+c holds row t, chunk c^(t&7)
  __shared__ f16 Bs[3 * 128 * 64];   // 49,152 B; 3 taps, same swizzled layout
  int tid = threadIdx.x;
  int nt = blockIdx.x & 7;
  int mt = blockIdx.x >> 3;          // 0..511
  int i  = mt >> 1;
  int j0 = (mt & 1) * 128;
  int n0 = nt * 128;
  int lane = tid & 63, wave = tid >> 6;
  int ln15 = lane & 15, quad = lane >> 4;
  int wm = wave & 1, wn = wave >> 1;

  f32x4 acc[4][4] = {};

  for (int di = 0; di < 3; ++di) {
    const f16* aRow = padx + ((size_t)(i + di) * 258 + j0) * 128;
    for (int kc = 0; kc < 128; kc += 64) {
      // ---- stage A: 130 rows x 8 chunks = 1040 slots (guarded 5th phase)
#pragma unroll
      for (int ph = 0; ph < 5; ++ph) {
        int s = ph * 256 + tid;
        if (s < 1040) {
          int rr = s >> 3;
          int qq = ((s & 7) ^ (rr & 7)) * 8;
          ldsdma16(&As[(ph * 256 + wave * 64) * 8], aRow + (size_t)rr * 128 + kc + qq);
        }
      }
      // ---- stage B: all 3 taps, 3072 slots
#pragma unroll
      for (int ph = 0; ph < 12; ++ph) {
        int s2 = ph * 256 + tid;
        int dj = s2 >> 10;
        int sB = s2 & 1023;
        int rr = sB >> 3;
        int qq = ((sB & 7) ^ (rr & 7)) * 8;
        ldsdma16(&Bs[(ph * 256 + wave * 64) * 8],
                 wcat + ((size_t)((di * 3 + dj) * 1024 + n0 + rr)) * 128 + kc + qq);
      }
      __syncthreads();
#pragma unroll
      for (int dj = 0; dj < 3; ++dj) {
#pragma unroll
        for (int ks = 0; ks < 2; ++ks) {
          int q = ks * 4 + quad;
          f16x8 af[4], bfr[4];
#pragma unroll
          for (int xx = 0; xx < 4; ++xx) {
            int t  = dj + wm * 64 + xx * 16 + ln15;
            int rb = wn * 64 + xx * 16 + ln15;
            af[xx]  = *(const f16x8*)(&As[t * 64 + ((q ^ (t & 7)) * 8)]);
            bfr[xx] = *(const f16x8*)(&Bs[dj * 8192 + rb * 64 + ((q ^ (rb & 7)) * 8)]);
          }
#pragma unroll
          for (int mf = 0; mf < 4; ++mf)
#pragma unroll
            for (int nf = 0; nf < 4; ++nf)
              acc[mf][nf] = __builtin_amdgcn_mfma_f32_16x16x32_f16(af[mf], bfr[nf],
                                                                   acc[mf][nf], 0, 0, 0);
        }
      }
      __syncthreads();
    }
  }

  size_t token0 = (size_t)i * 256 + j0;
  if (nt < 4) {
    // ---- fxT path: bias, transpose through LDS, f16x8 coalesced stores
    f16* tile = Bs;                  // [col 128][token 128] stride 136 (34,816 B)
#pragma unroll
    for (int nf = 0; nf < 4; ++nf) {
      int colLoc = wn * 64 + nf * 16 + ln15;
      float bias = bfx[n0 + colLoc];
#pragma unroll
      for (int mf = 0; mf < 4; ++mf) {
        int tokBase = wm * 64 + mf * 16 + quad * 4;
        f16x4 pk;
#pragma unroll
        for (int v = 0; v < 4; ++v) pk[v] = (f16)(acc[mf][nf][v] + bias);
        *(f16x4*)(&tile[colLoc * 136 + tokBase]) = pk;
      }
    }
    __syncthreads();
#pragma unroll
    for (int it2 = 0; it2 < 8; ++it2) {
      int s = it2 * 256 + tid;       // 0..2047
      int c = s >> 4, t8 = s & 15;
      f16x8 vv = *(const f16x8*)(&tile[c * 136 + t8 * 8]);
      *(f16x8*)(fxT + (size_t)(n0 + c) * 65536 + token0 + t8 * 8) = vv;
    }
  } else {
    // ---- xmid path: token-major rows, 128 B contiguous per token per wave
#pragma unroll
    for (int nf = 0; nf < 4; ++nf) {
      int col = n0 + wn * 64 + nf * 16 + ln15;
      float bias = bx[col - 512];
#pragma unroll
      for (int mf = 0; mf < 4; ++mf) {
        int rbase = wm * 64 + mf * 16 + quad * 4;
#pragma unroll
        for (int v = 0; v < 4; ++v)
          xmid[(size_t)(token0 + rbase + v) * 512 + (col - 512)] =
              (f16)(acc[mf][nf][v] + bias);
      }
    }
  }
}

// ---------------- slice: MFMA logits -> shfl softmax -> W overlay + MFMA ST acc
#define WS_S 72
#define WT_S 264
__global__ __launch_bounds__(256, 2) void slice_kernel(f16* __restrict__ xmid,
                                                       const f16* __restrict__ fxT,
                                                       const float* __restrict__ Wslice,
                                                       const float* __restrict__ bslice,
                                                       const float* __restrict__ temperature,
                                                       float* __restrict__ ST,
                                                       float* __restrict__ snorm) {
  __shared__ f16 Ws[64 * WS_S];      // [g][d] f16, padded
  __shared__ f16 Wt[64 * WT_S];      // [g][t_local 256] padded, wave-private t-stripes
  __shared__ float red[64 * 65];     // cross-wave ST reduction
  __shared__ float redn[64];
  int tid = threadIdx.x;
  int h = blockIdx.x >> 6;           // 8
  int chunk = blockIdx.x & 63;       // 64 chunks of 1024 tokens
  int tok0 = chunk * 1024;
  int lane = tid & 63, wave = tid >> 6;
  int ln15 = lane & 15, quad = lane >> 4;

  for (int s = tid; s < 4096; s += 256)
    Ws[(s >> 6) * WS_S + (s & 63)] = (f16)Wslice[s];
  if (tid < 64) redn[tid] = 0.f;
  float tc = temperature[h];
  tc = fminf(fmaxf(tc, 0.1f), 5.0f);
  float invt = 1.0f / tc;
  float bsv[4];
#pragma unroll
  for (int nf = 0; nf < 4; ++nf) bsv[nf] = bslice[nf * 16 + ln15];
  __syncthreads();

  f32x4 acc2[4][4] = {};             // ST partial: [mf->g][nf->d]
  float naccv[4] = {};               // norm partial per nf (g = nf*16+ln15)

  for (int it = 0; it < 4; ++it) {
    int tsub = it * 256 + wave * 64;            // this wave's 64 tokens (local)
    // ---- phase A: logits via MFMA (A direct from global, B from LDS Ws)
    f32x4 accA[4][4] = {};
#pragma unroll
    for (int kq = 0; kq < 2; ++kq) {
      f16x8 bf[4];
#pragma unroll
      for (int nf = 0; nf < 4; ++nf)
        bf[nf] = *(const f16x8*)(&Ws[(nf * 16 + ln15) * WS_S + kq * 32 + quad * 8]);
#pragma unroll
      for (int mf = 0; mf < 4; ++mf) {
        f16x8 af = *(const f16x8*)(xmid + (size_t)(tok0 + tsub + mf * 16 + ln15) * 512 +
                                   h * 64 + kq * 32 + quad * 8);
#pragma unroll
        for (int nf = 0; nf < 4; ++nf)
          accA[mf][nf] = __builtin_amdgcn_mfma_f32_16x16x32_f16(af, bf[nf], accA[mf][nf],
                                                                0, 0, 0);
      }
    }
    // ---- softmax over g (4 in-lane nf x 16 lanes), write W overlay + Wt
#pragma unroll
    for (int mf = 0; mf < 4; ++mf) {
#pragma unroll
      for (int v = 0; v < 4; ++v) {
        float l[4];
#pragma unroll
        for (int nf = 0; nf < 4; ++nf) l[nf] = (accA[mf][nf][v] + bsv[nf]) * invt;
        float lm = fmaxf(fmaxf(l[0], l[1]), fmaxf(l[2], l[3]));
#pragma unroll
        for (int off = 1; off < 16; off <<= 1) lm = fmaxf(lm, __shfl_xor(lm, off, 64));
        float e[4], ssum = 0.f;
#pragma unroll
        for (int nf = 0; nf < 4; ++nf) { e[nf] = __expf(l[nf] - lm); ssum += e[nf]; }
#pragma unroll
        for (int off = 1; off < 16; off <<= 1) ssum += __shfl_xor(ssum, off, 64);
        float winv = 1.0f / ssum;
        int t_loc = tsub + mf * 16 + quad * 4 + v;       // local to 1024-chunk
        int t_str = wave * 64 + mf * 16 + quad * 4 + v;  // local to 256-stripe set
        f16* wrow = xmid + (size_t)(tok0 + t_loc) * 512 + h * 64;
#pragma unroll
        for (int nf = 0; nf < 4; ++nf) {
          float w = e[nf] * winv;
          naccv[nf] += w;
          f16 wh = (f16)w;
          wrow[nf * 16 + ln15] = wh;
          Wt[(nf * 16 + ln15) * WT_S + t_str] = wh;
        }
      }
    }
    // ---- phase B: acc2[g][d] += Wt^T-frag x fxT-frag (wave-private k-range)
#pragma unroll
    for (int kq = 0; kq < 2; ++kq) {
      int kof = wave * 64 + kq * 32 + quad * 8;          // within 256-stripe set
      f16x8 bfB[4];
#pragma unroll
      for (int nf = 0; nf < 4; ++nf)
        bfB[nf] = *(const f16x8*)(fxT + (size_t)(h * 64 + nf * 16 + ln15) * 65536 +
                                  tok0 + it * 256 + kof);
#pragma unroll
      for (int mf = 0; mf < 4; ++mf) {
        f16x8 afB = *(const f16x8*)(&Wt[(mf * 16 + ln15) * WT_S + kof]);
#pragma unroll
        for (int nf = 0; nf < 4; ++nf)
          acc2[mf][nf] = __builtin_amdgcn_mfma_f32_16x16x32_f16(afB, bfB[nf],
                                                                acc2[mf][nf], 0, 0, 0);
      }
    }
  }

  // ---- norm partials into LDS (16 contributors per g)
#pragma unroll
  for (int nf = 0; nf < 4; ++nf) atomicAdd(&redn[nf * 16 + ln15], naccv[nf]);

  // ---- cross-wave ST reduce + global atomics
  for (int s = 0; s < 4; ++s) {
    if (wave == s) {
#pragma unroll
      for (int mf = 0; mf < 4; ++mf)
#pragma unroll
        for (int nf = 0; nf < 4; ++nf)
#pragma unroll
          for (int v = 0; v < 4; ++v) {
            int g = mf * 16 + quad * 4 + v;
            int d = nf * 16 + ln15;
            if (s == 0) red[g * 65 + d] = acc2[mf][nf][v];
            else        red[g * 65 + d] += acc2[mf][nf][v];
          }
    }
    __syncthreads();
  }
  float* stp = ST + (size_t)h * 4096;
  for (int s2 = tid; s2 < 4096; s2 += 256)
    atomicAdd(&stp[s2], red[(s2 >> 6) * 65 + (s2 & 63)]);
  if (tid < 64) atomicAdd(&snorm[h * 64 + tid], redn[tid]);
}

// ------------------------------------------ tiny attention over 64 slice tokens
__global__ __launch_bounds__(256) void attn_kernel(const float* __restrict__ ST,
                                                   const float* __restrict__ snorm,
                                                   const float* __restrict__ Wq,
                                                   const float* __restrict__ Wk,
                                                   const float* __restrict__ Wv,
                                                   float* __restrict__ OS) {
  int h = blockIdx.x;                // 8
  __shared__ float tok[64 * 65];     // aliased as scores later
  __shared__ float qs[64 * 65];
  __shared__ float ksm[64 * 65];
  __shared__ f16 vsm[64 * 65];
  int tid = threadIdx.x;
  const float* stp = ST + (size_t)h * 4096;
  const float* snp = snorm + (size_t)h * 64;
  for (int s = tid; s < 4096; s += 256) {
    int g = s >> 6, d = s & 63;
    tok[g * 65 + d] = stp[s] / (snp[g] + 1e-5f);
  }
  __syncthreads();
  int g = tid >> 2, p16 = (tid & 3) * 16;
  for (int e0 = 0; e0 < 16; ++e0) {
    int e = p16 + e0;
    const float* wq = Wq + e * 64;
    const float* wk = Wk + e * 64;
    const float* wv = Wv + e * 64;
    float aq = 0, ak = 0, av = 0;
#pragma unroll 8
    for (int d = 0; d < 64; ++d) {
      float tv = tok[g * 65 + d];
      aq += tv * wq[d];
      ak += tv * wk[d];
      av += tv * wv[d];
    }
    qs[g * 65 + e] = aq;
    ksm[g * 65 + e] = ak;
    vsm[g * 65 + e] = (f16)av;
  }
  __syncthreads();
  float* sc = tok;  // alias, tok dead
  for (int f0 = 0; f0 < 16; ++f0) {
    int f = p16 + f0;
    float s = 0;
#pragma unroll 8
    for (int e = 0; e < 64; ++e) s += qs[g * 65 + e] * ksm[f * 65 + e];
    sc[g * 65 + f] = s * 0.125f;
  }
  __syncthreads();
  if (tid < 64) {
    float m = -1e30f;
    for (int f = 0; f < 64; ++f) m = fmaxf(m, sc[tid * 65 + f]);
    float ssum = 0;
    for (int f = 0; f < 64; ++f) {
      float e = __expf(sc[tid * 65 + f] - m);
      sc[tid * 65 + f] = e;
      ssum += e;
    }
    float inv = 1.0f / ssum;
    for (int f = 0; f < 64; ++f) sc[tid * 65 + f] *= inv;
  }
  __syncthreads();
  for (int e0 = 0; e0 < 16; ++e0) {
    int e = p16 + e0;
    float o = 0;
#pragma unroll 8
    for (int f = 0; f < 64; ++f) o += sc[g * 65 + f] * (float)vsm[f * 65 + e];
    OS[(size_t)h * 4096 + g * 64 + e] = o;
  }
}

// -------------------------- fold out_slice into Wout: PT[o][h*64+g] (f16)
__global__ __launch_bounds__(256) void pt_kernel(const float* __restrict__ OS,
                                                 const float* __restrict__ Wout,
                                                 f16* __restrict__ PT) {
  int h = blockIdx.x;                // 8
  __shared__ float os[64 * 65];
  int tid = threadIdx.x;
  for (int s = tid; s < 4096; s += 256) os[(s >> 6) * 65 + (s & 63)] = OS[(size_t)h * 4096 + s];
  __syncthreads();
  int o = tid >> 1, gh = (tid & 1) * 32;
  const float* wr = Wout + (size_t)o * 512 + h * 64;
  float wreg[64];
#pragma unroll
  for (int d = 0; d < 64; ++d) wreg[d] = wr[d];
  for (int gg = 0; gg < 32; ++gg) {
    int g = gh + gg;
    float s = 0;
#pragma unroll
    for (int d = 0; d < 64; ++d) s += os[g * 65 + d] * wreg[d];
    PT[(size_t)o * 512 + h * 64 + g] = (f16)s;
  }
}

// -------------------- final: out[n,o] = sum_k W[n,k] * PT[o,k] + bout[o]
__global__ __launch_bounds__(256, 2) void final_kernel(const f16* __restrict__ xmid,
                                                       const f16* __restrict__ PT,
                                                       const float* __restrict__ bout,
                                                       float* __restrict__ outb) {
  __shared__ f16 As[128 * 64];
  __shared__ f16 Bs[128 * 64];
  int tid = threadIdx.x;
  int tok0 = blockIdx.x << 7;        // 512 blocks
  int lane = tid & 63, wave = tid >> 6;
  int ln15 = lane & 15, quad = lane >> 4;
  int wm = wave & 1, wn = wave >> 1;
  int rr[4], qq8[4];
#pragma unroll
  for (int ph = 0; ph < 4; ++ph) {
    int s = ph * 256 + tid;
    rr[ph] = s >> 3;
    qq8[ph] = ((s & 7) ^ (rr[ph] & 7)) * 8;
  }
  int wbase = wave * 512;
  f32x4 acc[4][4] = {};
  const f16* aB = xmid + (size_t)tok0 * 512;
  const f16* bB = PT;
  for (int kc = 0; kc < 512; kc += 64) {
#pragma unroll
    for (int ph = 0; ph < 4; ++ph) {
      ldsdma16(&As[ph * 2048 + wbase], aB + (size_t)rr[ph] * 512 + kc + qq8[ph]);
      ldsdma16(&Bs[ph * 2048 + wbase], bB + (size_t)rr[ph] * 512 + kc + qq8[ph]);
    }
    __syncthreads();
#pragma unroll
    for (int ks = 0; ks < 2; ++ks) {
      f16x8 af[4], bfr[4];
      int q = ks * 4 + quad;
#pragma unroll
      for (int xx = 0; xx < 4; ++xx) {
        int ra = wm * 64 + xx * 16 + ln15;
        int rb = wn * 64 + xx * 16 + ln15;
        af[xx]  = *(const f16x8*)(&As[ra * 64 + (q ^ (ra & 7)) * 8]);
        bfr[xx] = *(const f16x8*)(&Bs[rb * 64 + (q ^ (rb & 7)) * 8]);
      }
#pragma unroll
      for (int mf = 0; mf < 4; ++mf)
#pragma unroll
        for (int nf = 0; nf < 4; ++nf)
          acc[mf][nf] = __builtin_amdgcn_mfma_f32_16x16x32_f16(af[mf], bfr[nf],
                                                               acc[mf][nf], 0, 0, 0);
    }
    __syncthreads();
  }
#pragma unroll
  for (int nf = 0; nf < 4; ++nf) {
    int col = wn * 64 + nf * 16 + ln15;
    float bo = bout[col];
#pragma unroll
    for (int mf = 0; mf < 4; ++mf) {
      int rbase = wm * 64 + mf * 16 + quad * 4;
#pragma unroll
      for (int v = 0; v < 4; ++v)
        outb[(size_t)(tok0 + rbase + v) * 128 + col] = acc[mf][nf][v] + bo;
    }
  }
}

extern "C" void kernel_launch(void* const* d_in, const int* in_sizes, int n_in,
                              void* d_out, int out_size, void* d_ws, size_t ws_size,
                              hipStream_t stream) {
  const float* x    = (const float*)d_in[0];
  const float* Wfx  = (const float*)d_in[1];
  const float* bfx  = (const float*)d_in[2];
  const float* Wx   = (const float*)d_in[3];
  const float* bx   = (const float*)d_in[4];
  const float* Wsl  = (const float*)d_in[5];
  const float* bsl  = (const float*)d_in[6];
  const float* temp = (const float*)d_in[7];
  const float* Wq   = (const float*)d_in[8];
  const float* Wk   = (const float*)d_in[9];
  const float* Wv   = (const float*)d_in[10];
  const float* Wout = (const float*)d_in[11];
  const float* bout = (const float*)d_in[12];
  float* out = (float*)d_out;
  char* ws = (char*)d_ws;

  f16*  padx = (f16*)(ws + OFF_PADX);
  f16*  wcat = (f16*)(ws + OFF_WCAT);
  float* ST  = (float*)(ws + OFF_ST);
  float* nrm = (float*)(ws + OFF_NORM);
  float* OS  = (float*)(ws + OFF_OS);
  f16*  PT   = (f16*)(ws + OFF_PT);
  f16*  xmid = (f16*)(ws + OFF_XMID);
  f16*  fxT  = (f16*)(ws + OFF_FXT);

  prepw_kernel<<<4608, 256, 0, stream>>>(Wfx, Wx, wcat);
  for (int b = 0; b < 2; ++b) {
    const float* xb = x + (size_t)b * 65536 * 128;
    float* outb = out + (size_t)b * 65536 * 128;
    hipMemsetAsync(ws + OFF_ST, 0, 131072 + 2048, stream);  // ST + norm
    pad_kernel<<<4161, 256, 0, stream>>>(xb, padx);
    conv_kernel<<<4096, 256, 0, stream>>>(padx, wcat, bfx, bx, xmid, fxT);
    slice_kernel<<<512, 256, 0, stream>>>(xmid, fxT, Wsl, bsl, temp, ST, nrm);
    attn_kernel<<<8, 256, 0, stream>>>(ST, nrm, Wq, Wk, Wv, OS);
    pt_kernel<<<8, 256, 0, stream>>>(OS, Wout, PT);
    final_kernel<<<512, 256, 0, stream>>>(xmid, PT, bout, outb);
  }
}